// Round 10
// baseline (485.897 us; speedup 1.0000x reference)
//
#include <hip/hip_runtime.h>
#include <hip/hip_cooperative_groups.h>
#include <math.h>

namespace cg = cooperative_groups;

constexpr int NV   = 100000;
constexpr int NEg  = 20000;
constexpr int NNZp = 1600000;
constexpr int NF   = 128;
constexpr int NH   = 64;
constexpr int NC   = 40;

constexpr int WE  = 64;                       // e-bucket width (2^6)
constexpr int NBE = (NEg + WE - 1) / WE;      // 313
constexpr int WV  = 256;                      // v-bucket width (2^8)
constexpr int NBV = (NV + WV - 1) / WV;       // 391
constexpr int CAPS = 6400;                    // local_sort stage cap
constexpr int CHB  = 4096;                    // build chunk per block
constexpr int GB   = (NNZp + CHB - 1) / CHB;  // 391 blocks (co-resident at ~26KB LDS)

typedef __bf16 bf16x8 __attribute__((ext_vector_type(8)));
typedef float  f32x4  __attribute__((ext_vector_type(4)));

// ---- bf16 <-> fp32 helpers (RNE) ----
__device__ __forceinline__ float bf2f(unsigned short u) {
    unsigned int x = ((unsigned int)u) << 16;
    return __builtin_bit_cast(float, x);
}
__device__ __forceinline__ unsigned short f2bf(float f) {
    unsigned int x = __builtin_bit_cast(unsigned int, f);
    x += 0x7fffu + ((x >> 16) & 1u);
    return (unsigned short)(x >> 16);
}
__device__ __forceinline__ ushort4 pack4(float a, float b, float c, float d) {
    ushort4 u; u.x = f2bf(a); u.y = f2bf(b); u.z = f2bf(c); u.w = f2bf(d);
    return u;
}

// ---- inclusive scan of src[0..m) (m<=512) into sc[512] with 256 threads ------
__device__ __forceinline__ void scan512(const int* src, int m, int* sc) {
    const int t = threadIdx.x;
    __syncthreads();                       // protect prior readers of sc
    sc[t]       = (t < m) ? src[t] : 0;
    sc[t + 256] = (t + 256 < m) ? src[t + 256] : 0;
    __syncthreads();
    for (int o = 1; o < 512; o <<= 1) {
        int a = (t >= o) ? sc[t - o] : 0;
        int b = (t + 256 >= o) ? sc[t + 256 - o] : 0;
        __syncthreads();
        sc[t] += a;
        sc[t + 256] += b;
        __syncthreads();
    }
}

// ---- cooperative fused CSR build: hist + scan + partition (one data read) ----
__global__ __launch_bounds__(256) void build_coop(const int* __restrict__ vertex,
                                                  const int* __restrict__ edges,
                                                  int* __restrict__ cnt_be,
                                                  int* __restrict__ cnt_bv,
                                                  int* __restrict__ gcur_e,
                                                  int* __restrict__ gcur_v,
                                                  int* __restrict__ rsb_e,
                                                  int* __restrict__ rsb_v,
                                                  int* __restrict__ rs_e,
                                                  int* __restrict__ rs_v,
                                                  int* __restrict__ vid_out,
                                                  int* __restrict__ eid_out) {
    __shared__ int harr_e[NBE], harr_v[NBV];   // block-local histograms
    __shared__ int gb[NBV], off[NBV], curr[NBV];
    __shared__ int sc[512];
    __shared__ int stage[CHB];                 // 16 KB, reused e-side then v-side
    const int tid = threadIdx.x;
    const int base = blockIdx.x * CHB;
    const int n = min(NNZp - base, CHB);

    for (int i = tid; i < NBE; i += 256) harr_e[i] = 0;
    for (int i = tid; i < NBV; i += 256) harr_v[i] = 0;
    __syncthreads();

    int re[16], rv[16];
#pragma unroll
    for (int j = 0; j < 16; ++j) {
        int i = j * 256 + tid;
        bool ok = i < n;
        re[j] = ok ? edges[base + i] : -1;
        rv[j] = ok ? vertex[base + i] : -1;
        if (ok) {
            atomicAdd(&harr_e[re[j] >> 6], 1);
            atomicAdd(&harr_v[rv[j] >> 8], 1);
        }
    }
    __syncthreads();
    for (int i = tid; i < NBE; i += 256) if (harr_e[i]) atomicAdd(&cnt_be[i], harr_e[i]);
    for (int i = tid; i < NBV; i += 256) if (harr_v[i]) atomicAdd(&cnt_bv[i], harr_v[i]);

    cg::this_grid().sync();

    // ================= e side =================
    scan512(cnt_be, NBE, sc);                  // inclusive scan of global counts
    if (blockIdx.x == 0) {
        for (int k = tid; k < NBE; k += 256) rsb_e[k] = sc[k] - cnt_be[k];
        if (tid == 0) { rsb_e[NBE] = NNZp; rs_e[NEg] = NNZp; }
    }
    for (int k = tid; k < NBE; k += 256) {
        int h = harr_e[k];
        gb[k] = (sc[k] - cnt_be[k]) + (h ? atomicAdd(&gcur_e[k], h) : 0);
    }
    scan512(harr_e, NBE, sc);                  // in-block offsets
    for (int k = tid; k < NBE; k += 256) {
        int o = sc[k] - harr_e[k];
        off[k] = o; curr[k] = o;
    }
    __syncthreads();
#pragma unroll
    for (int j = 0; j < 16; ++j) {
        if (re[j] >= 0) {
            int k = re[j] >> 6;
            int p = atomicAdd(&curr[k], 1);
            stage[p] = (int)(((unsigned)rv[j] << 15) | (unsigned)re[j]);
        }
    }
    __syncthreads();
    for (int i = tid; i < n; i += 256) {       // stage-ordered -> mostly coalesced
        unsigned w = (unsigned)stage[i];
        int e = (int)(w & 0x7fffu);
        int k = e >> 6;
        vid_out[gb[k] + (i - off[k])] = (int)(((w >> 15) << 6) | (unsigned)(e & 63));
    }
    __syncthreads();

    // ================= v side =================
    scan512(cnt_bv, NBV, sc);
    if (blockIdx.x == 0) {
        for (int k = tid; k < NBV; k += 256) rsb_v[k] = sc[k] - cnt_bv[k];
        if (tid == 0) { rsb_v[NBV] = NNZp; rs_v[NV] = NNZp; }
    }
    for (int k = tid; k < NBV; k += 256) {
        int h = harr_v[k];
        gb[k] = (sc[k] - cnt_bv[k]) + (h ? atomicAdd(&gcur_v[k], h) : 0);
    }
    scan512(harr_v, NBV, sc);
    for (int k = tid; k < NBV; k += 256) {
        int o = sc[k] - harr_v[k];
        off[k] = o; curr[k] = o;
    }
    __syncthreads();
#pragma unroll
    for (int j = 0; j < 16; ++j) {
        if (rv[j] >= 0) {
            int k = rv[j] >> 8;
            int p = atomicAdd(&curr[k], 1);
            stage[p] = (int)(((unsigned)re[j] << 17) | (unsigned)rv[j]);
        }
    }
    __syncthreads();
    for (int i = tid; i < n; i += 256) {
        unsigned w = (unsigned)stage[i];
        int v = (int)(w & 0x1ffffu);
        int k = v >> 8;
        eid_out[gb[k] + (i - off[k])] = (int)(((w >> 17) << 8) | (unsigned)(v & 255));
    }
}

// ------- fused per-bucket LDS counting sort -----------------------------------
__global__ __launch_bounds__(512) void local_sort_both(const int* __restrict__ rsb_e,
                                                       const int* __restrict__ rsb_v,
                                                       int* __restrict__ vid_buf,
                                                       int* __restrict__ eid_buf,
                                                       int* __restrict__ rs_e,
                                                       int* __restrict__ rs_v,
                                                       const float* __restrict__ degE,
                                                       float* __restrict__ scaleE) {
    __shared__ int stage[CAPS];
    __shared__ int hist[256], off[256], cnt2[256];
    const bool eside = blockIdx.x < NBE;
    const int b   = eside ? blockIdx.x : blockIdx.x - NBE;
    const int W   = eside ? 64 : 256;
    const int FB  = eside ? 6 : 8;
    const int NID = eside ? NEg : NV;
    const int* rsb = eside ? rsb_e : rsb_v;
    int* buf       = eside ? vid_buf : eid_buf;
    int* rs        = eside ? rs_e : rs_v;
    const int base = rsb[b];
    const int sz   = rsb[b + 1] - base;
    const int tid = threadIdx.x;
    if (tid < 256) { hist[tid] = 0; cnt2[tid] = 0; }
    __syncthreads();
    for (int t = tid; t < sz; t += 512) atomicAdd(&hist[buf[base + t] & (W - 1)], 1);
    __syncthreads();
    {
        int v = (tid < W) ? hist[tid] : 0;
        if (tid < W) off[tid] = v;
        __syncthreads();
        for (int o = 1; o < W; o <<= 1) {
            int u = (tid < W && tid >= o) ? off[tid - o] : 0;
            __syncthreads();
            if (tid < W) off[tid] += u;
            __syncthreads();
        }
        if (tid < W) off[tid] -= v;
    }
    if (tid < W) {
        int gid = b * W + tid;
        if (gid < NID) {
            rs[gid] = base + off[tid];
            if (eside) {
                int c = hist[tid];
                scaleE[gid] = degE[gid] / (float)(c < 1 ? 1 : c);
            }
        }
    }
    __syncthreads();
    for (int t = tid; t < sz; t += 512) {
        int w = buf[base + t];
        int f = w & (W - 1);
        int rk = off[f] + atomicAdd(&cnt2[f], 1);
        stage[rk] = w >> FB;
    }
    __syncthreads();
    for (int t = tid; t < sz; t += 512) buf[base + t] = stage[t];
}

// ------- W fragments (B-operand layout, bf16): Ws MLPs + head + W0 ------------
__global__ __launch_bounds__(256) void make_wfrag(const float* __restrict__ Ws,
                                                  const float* __restrict__ Wout,
                                                  const float* __restrict__ W0,
                                                  unsigned short* __restrict__ frag) {
    int t = blockIdx.x * 256 + threadIdx.x;     // 3584 threads exactly
    int lane = t & 63;
    int g = t >> 6;                             // 0..55
    int quad = lane >> 4, cl = lane & 15;
    unsigned short o[8];
    if (g < 32) {
        int li = g >> 3, w = (g >> 1) & 3, kh = g & 1;
        int n = w * 16 + cl;
#pragma unroll
        for (int j = 0; j < 8; ++j) {
            int k = kh * 32 + quad * 8 + j;
            o[j] = f2bf(Ws[(size_t)li * NH * NH + k * NH + n]);
        }
    } else if (g < 40) {
        int w = (g - 32) >> 1, kh = g & 1;
        int n = w * 16 + cl;
#pragma unroll
        for (int j = 0; j < 8; ++j) {
            int k = kh * 32 + quad * 8 + j;
            o[j] = (n < NC) ? f2bf(Wout[k * NC + n]) : (unsigned short)0;
        }
    } else {
        int w = (g - 40) >> 2, kb = (g - 40) & 3;
        int n = w * 16 + cl;
#pragma unroll
        for (int j = 0; j < 8; ++j) {
            int k = kb * 32 + quad * 8 + j;
            o[j] = f2bf(W0[k * NH + n]);
        }
    }
    unsigned short* dst = frag + (size_t)g * 512 + lane * 8;
    *((ushort4*)dst)       = *(ushort4*)&o[0];
    *((ushort4*)(dst + 4)) = *(ushort4*)&o[4];
}

// ---------------- X = relu(x @ W0 + b0) via MFMA; Xbf = X0bf ------------------
__global__ __launch_bounds__(256) void gemm0_kernel(const float* __restrict__ x,
                                                    const unsigned short* __restrict__ W0frag,
                                                    const float* __restrict__ b0,
                                                    unsigned short* __restrict__ Xbf,
                                                    unsigned short* __restrict__ X0bf) {
    __shared__ unsigned short xs[16][136];    // bf16, stride 136 (16B-aligned rows)
    const int tid = threadIdx.x;
    const int r  = tid >> 4;
    const int c8 = (tid & 15) * 8;
    const int rowbase = blockIdx.x * 16;      // grid = NV/16 exact
    float4 p0 = *((const float4*)(x + (size_t)(rowbase + r) * NF + c8));
    float4 p1 = *((const float4*)(x + (size_t)(rowbase + r) * NF + c8 + 4));
    *((ushort4*)&xs[r][c8])     = pack4(p0.x, p0.y, p0.z, p0.w);
    *((ushort4*)&xs[r][c8 + 4]) = pack4(p1.x, p1.y, p1.z, p1.w);
    __syncthreads();
    const int lane = tid & 63;
    const int wv   = tid >> 6;
    const int quad = lane >> 4;
    const int cl   = lane & 15;
    f32x4 acc = {0.f, 0.f, 0.f, 0.f};
#pragma unroll
    for (int kb = 0; kb < 4; ++kb) {
        bf16x8 a = *((const bf16x8*)&xs[cl][kb * 32 + quad * 8]);
        bf16x8 b = *((const bf16x8*)(W0frag + ((size_t)(wv * 4 + kb) * 64 + lane) * 8));
        acc = __builtin_amdgcn_mfma_f32_16x16x32_bf16(a, b, acc, 0, 0, 0);
    }
    const int col = wv * 16 + cl;
    const float bo = b0[col];
#pragma unroll
    for (int p = 0; p < 4; ++p) {
        const int orow = quad * 4 + p;
        float o = acc[p] + bo;
        o = o > 0.f ? o : 0.f;
        unsigned short ob = f2bf(o);
        const size_t idx = (size_t)(rowbase + orow) * NH + col;
        Xbf[idx]  = ob;
        X0bf[idx] = ob;
    }
}

// ---------------- v->e gather -------------------------------------------------
__global__ __launch_bounds__(256) void gather_ve(const int* __restrict__ rs_e,
                                                 const int* __restrict__ vid_sorted,
                                                 const unsigned short* __restrict__ Xbf,
                                                 const float* __restrict__ scaleE,
                                                 unsigned short* __restrict__ Xebf) {
    const int tid = threadIdx.x;
    const int l16 = tid & 15;
    const int e = blockIdx.x * 16 + (tid >> 4);   // grid = NE/16 exact
    const int b  = rs_e[e];
    const int en = rs_e[e + 1];
    const float s = scaleE[e];
    float ax = 0.f, ay = 0.f, az = 0.f, aw = 0.f;
    int m = b;
    if (m + 4 <= en) {
        int i0 = vid_sorted[m], i1 = vid_sorted[m + 1];
        int i2 = vid_sorted[m + 2], i3 = vid_sorted[m + 3];
        m += 4;
        while (m + 4 <= en) {
            int j0 = vid_sorted[m], j1 = vid_sorted[m + 1];
            int j2 = vid_sorted[m + 2], j3 = vid_sorted[m + 3];
            m += 4;
            ushort4 p = *((const ushort4*)(Xbf + (size_t)i0 * NH) + l16);
            ushort4 q = *((const ushort4*)(Xbf + (size_t)i1 * NH) + l16);
            ushort4 u = *((const ushort4*)(Xbf + (size_t)i2 * NH) + l16);
            ushort4 t = *((const ushort4*)(Xbf + (size_t)i3 * NH) + l16);
            ax += bf2f(p.x) + bf2f(q.x) + bf2f(u.x) + bf2f(t.x);
            ay += bf2f(p.y) + bf2f(q.y) + bf2f(u.y) + bf2f(t.y);
            az += bf2f(p.z) + bf2f(q.z) + bf2f(u.z) + bf2f(t.z);
            aw += bf2f(p.w) + bf2f(q.w) + bf2f(u.w) + bf2f(t.w);
            i0 = j0; i1 = j1; i2 = j2; i3 = j3;
        }
        ushort4 p = *((const ushort4*)(Xbf + (size_t)i0 * NH) + l16);
        ushort4 q = *((const ushort4*)(Xbf + (size_t)i1 * NH) + l16);
        ushort4 u = *((const ushort4*)(Xbf + (size_t)i2 * NH) + l16);
        ushort4 t = *((const ushort4*)(Xbf + (size_t)i3 * NH) + l16);
        ax += bf2f(p.x) + bf2f(q.x) + bf2f(u.x) + bf2f(t.x);
        ay += bf2f(p.y) + bf2f(q.y) + bf2f(u.y) + bf2f(t.y);
        az += bf2f(p.z) + bf2f(q.z) + bf2f(u.z) + bf2f(t.z);
        aw += bf2f(p.w) + bf2f(q.w) + bf2f(u.w) + bf2f(t.w);
    }
    for (; m < en; ++m) {
        ushort4 p = *((const ushort4*)(Xbf + (size_t)vid_sorted[m] * NH) + l16);
        ax += bf2f(p.x); ay += bf2f(p.y); az += bf2f(p.z); aw += bf2f(p.w);
    }
    *((ushort4*)(Xebf + (size_t)e * NH) + l16) = pack4(ax * s, ay * s, az * s, aw * s);
}

// ---------------- e->v gather + normalize/residual + MFMA MLP (+head) ----------
template <bool LAST>
__global__ __launch_bounds__(256) void gather_ev_update(const int* __restrict__ rs_v,
                                                        const int* __restrict__ eid_sorted,
                                                        const unsigned short* __restrict__ Xebf,
                                                        const float* __restrict__ degV,
                                                        const unsigned short* __restrict__ X0bf,
                                                        const unsigned short* __restrict__ WfragL,
                                                        unsigned short* __restrict__ Xbf,
                                                        float beta,
                                                        const unsigned short* __restrict__ WfragH,
                                                        const float* __restrict__ bout,
                                                        float* __restrict__ outp) {
    __shared__ unsigned short xis_bf[16][72];              // bf16, stride 72 (2-way only)
    __shared__ unsigned short xo_bf[LAST ? 16 * 72 : 1];   // final X (LAST only)
    __shared__ float lg[LAST ? 16 * 48 : 1];               // logits (LAST only)
    const int tid = threadIdx.x;
    const int l16 = tid & 15;
    const int r   = tid >> 4;
    const int v = blockIdx.x * 16 + r;        // grid = NV/16 exact
    const int b  = rs_v[v];
    const int en = rs_v[v + 1];
    const float dv = degV[v];
    float ax = 0.f, ay = 0.f, az = 0.f, aw = 0.f;
    int m = b;
    if (m + 4 <= en) {
        int i0 = eid_sorted[m], i1 = eid_sorted[m + 1];
        int i2 = eid_sorted[m + 2], i3 = eid_sorted[m + 3];
        m += 4;
        while (m + 4 <= en) {
            int j0 = eid_sorted[m], j1 = eid_sorted[m + 1];
            int j2 = eid_sorted[m + 2], j3 = eid_sorted[m + 3];
            m += 4;
            ushort4 p = *((const ushort4*)(Xebf + (size_t)i0 * NH) + l16);
            ushort4 q = *((const ushort4*)(Xebf + (size_t)i1 * NH) + l16);
            ushort4 u = *((const ushort4*)(Xebf + (size_t)i2 * NH) + l16);
            ushort4 t = *((const ushort4*)(Xebf + (size_t)i3 * NH) + l16);
            ax += bf2f(p.x) + bf2f(q.x) + bf2f(u.x) + bf2f(t.x);
            ay += bf2f(p.y) + bf2f(q.y) + bf2f(u.y) + bf2f(t.y);
            az += bf2f(p.z) + bf2f(q.z) + bf2f(u.z) + bf2f(t.z);
            aw += bf2f(p.w) + bf2f(q.w) + bf2f(u.w) + bf2f(t.w);
            i0 = j0; i1 = j1; i2 = j2; i3 = j3;
        }
        ushort4 p = *((const ushort4*)(Xebf + (size_t)i0 * NH) + l16);
        ushort4 q = *((const ushort4*)(Xebf + (size_t)i1 * NH) + l16);
        ushort4 u = *((const ushort4*)(Xebf + (size_t)i2 * NH) + l16);
        ushort4 t = *((const ushort4*)(Xebf + (size_t)i3 * NH) + l16);
        ax += bf2f(p.x) + bf2f(q.x) + bf2f(u.x) + bf2f(t.x);
        ay += bf2f(p.y) + bf2f(q.y) + bf2f(u.y) + bf2f(t.y);
        az += bf2f(p.z) + bf2f(q.z) + bf2f(u.z) + bf2f(t.z);
        aw += bf2f(p.w) + bf2f(q.w) + bf2f(u.w) + bf2f(t.w);
    }
    for (; m < en; ++m) {
        ushort4 p = *((const ushort4*)(Xebf + (size_t)eid_sorted[m] * NH) + l16);
        ax += bf2f(p.x); ay += bf2f(p.y); az += bf2f(p.z); aw += bf2f(p.w);
    }
    ax *= dv; ay *= dv; az *= dv; aw *= dv;
    float sq = ax * ax + ay * ay + az * az + aw * aw;
#pragma unroll
    for (int o = 1; o < 16; o <<= 1) sq += __shfl_xor(sq, o);
    float norm = sqrtf(sq);
    float inv = norm > 0.f ? 1.f / norm : 0.f;
    ushort4 u0 = *((const ushort4*)(X0bf + (size_t)v * NH) + l16);
    float xi0 = 0.9f * ax * inv + 0.1f * bf2f(u0.x);
    float xi1 = 0.9f * ay * inv + 0.1f * bf2f(u0.y);
    float xi2 = 0.9f * az * inv + 0.1f * bf2f(u0.z);
    float xi3 = 0.9f * aw * inv + 0.1f * bf2f(u0.w);
    *((ushort4*)&xis_bf[r][l16 * 4]) = pack4(xi0, xi1, xi2, xi3);
    __syncthreads();

    // ---- MFMA MLP: g = xi @ Wl  (M=16, N=64, K=64) ----
    const int lane = tid & 63;
    const int wv   = tid >> 6;
    const int quad = lane >> 4;
    const int cl   = lane & 15;
    bf16x8 bw0 = *((const bf16x8*)(WfragL + ((size_t)(wv * 2 + 0) * 64 + lane) * 8));
    bf16x8 bw1 = *((const bf16x8*)(WfragL + ((size_t)(wv * 2 + 1) * 64 + lane) * 8));
    bf16x8 a0 = *((const bf16x8*)&xis_bf[cl][quad * 8]);
    bf16x8 a1 = *((const bf16x8*)&xis_bf[cl][32 + quad * 8]);
    f32x4 acc = {0.f, 0.f, 0.f, 0.f};
    acc = __builtin_amdgcn_mfma_f32_16x16x32_bf16(a0, bw0, acc, 0, 0, 0);
    acc = __builtin_amdgcn_mfma_f32_16x16x32_bf16(a1, bw1, acc, 0, 0, 0);

    const float ob = 1.f - beta;
    const int col = wv * 16 + cl;
#pragma unroll
    for (int p = 0; p < 4; ++p) {
        const int row = quad * 4 + p;
        float xiv = bf2f(xis_bf[row][col]);
        float o = ob * xiv + beta * acc[p];
        o = o > 0.f ? o : 0.f;
        if (!LAST) {
            Xbf[(size_t)(blockIdx.x * 16 + row) * NH + col] = f2bf(o);
        } else {
            xo_bf[row * 72 + col] = f2bf(o);
        }
    }
    if (LAST) {
        __syncthreads();
        // ---- MFMA output head: logits = Xfinal @ Wout (N padded to 64) ----
        bf16x8 bh0 = *((const bf16x8*)(WfragH + ((size_t)(wv * 2 + 0) * 64 + lane) * 8));
        bf16x8 bh1 = *((const bf16x8*)(WfragH + ((size_t)(wv * 2 + 1) * 64 + lane) * 8));
        bf16x8 ah0 = *((const bf16x8*)&xo_bf[cl * 72 + quad * 8]);
        bf16x8 ah1 = *((const bf16x8*)&xo_bf[cl * 72 + 32 + quad * 8]);
        f32x4 acch = {0.f, 0.f, 0.f, 0.f};
        acch = __builtin_amdgcn_mfma_f32_16x16x32_bf16(ah0, bh0, acch, 0, 0, 0);
        acch = __builtin_amdgcn_mfma_f32_16x16x32_bf16(ah1, bh1, acch, 0, 0, 0);
        if (col < NC) {
            float bo = bout[col];
#pragma unroll
            for (int p = 0; p < 4; ++p) lg[(quad * 4 + p) * 48 + col] = acch[p] + bo;
        }
        __syncthreads();
        // ---- log_softmax: each wave handles 4 rows ----
        const int r0 = wv * 4;
        const bool act = lane < NC;
        float a0s = act ? lg[(r0 + 0) * 48 + lane] : -INFINITY;
        float a1s = act ? lg[(r0 + 1) * 48 + lane] : -INFINITY;
        float a2s = act ? lg[(r0 + 2) * 48 + lane] : -INFINITY;
        float a3s = act ? lg[(r0 + 3) * 48 + lane] : -INFINITY;
        float m0 = a0s, m1 = a1s, m2 = a2s, m3 = a3s;
#pragma unroll
        for (int o = 32; o; o >>= 1) {
            m0 = fmaxf(m0, __shfl_xor(m0, o));
            m1 = fmaxf(m1, __shfl_xor(m1, o));
            m2 = fmaxf(m2, __shfl_xor(m2, o));
            m3 = fmaxf(m3, __shfl_xor(m3, o));
        }
        float e0 = act ? expf(a0s - m0) : 0.f;
        float e1 = act ? expf(a1s - m1) : 0.f;
        float e2 = act ? expf(a2s - m2) : 0.f;
        float e3 = act ? expf(a3s - m3) : 0.f;
#pragma unroll
        for (int o = 32; o; o >>= 1) {
            e0 += __shfl_xor(e0, o);
            e1 += __shfl_xor(e1, o);
            e2 += __shfl_xor(e2, o);
            e3 += __shfl_xor(e3, o);
        }
        if (act) {
            const size_t vb = (size_t)(blockIdx.x * 16 + r0) * NC + lane;
            outp[vb + 0 * NC] = a0s - m0 - logf(e0);
            outp[vb + 1 * NC] = a1s - m1 - logf(e1);
            outp[vb + 2 * NC] = a2s - m2 - logf(e2);
            outp[vb + 3 * NC] = a3s - m3 - logf(e3);
        }
    }
}

extern "C" void kernel_launch(void* const* d_in, const int* in_sizes, int n_in,
                              void* d_out, int out_size, void* d_ws, size_t ws_size,
                              hipStream_t stream) {
    const float* x    = (const float*)d_in[0];
    const float* degE = (const float*)d_in[1];
    const float* degV = (const float*)d_in[2];
    const float* W0   = (const float*)d_in[3];
    const float* b0   = (const float*)d_in[4];
    const float* Ws   = (const float*)d_in[5];
    const float* Wout = (const float*)d_in[6];
    const float* bout = (const float*)d_in[7];
    const int* vertex = (const int*)d_in[8];
    const int* edges  = (const int*)d_in[9];
    float* out = (float*)d_out;

    // workspace layout
    float* scaleE = (float*)d_ws;                              // NEg
    unsigned short* Xbf  = (unsigned short*)(scaleE + NEg);    // NV*NH bf16
    unsigned short* X0bf = Xbf + (size_t)NV * NH;
    unsigned short* Xebf = X0bf + (size_t)NV * NH;             // NE*NH bf16
    int* cnt_be = (int*)(Xebf + (size_t)NEg * NH);
    int* cnt_bv = cnt_be + NBE;
    int* gcur_e = cnt_bv + NBV;
    int* gcur_v = gcur_e + NBE;
    int* rsb_e  = gcur_v + NBV;
    int* rsb_v  = rsb_e + (NBE + 1);
    int* rs_e   = rsb_v + (NBV + 1);
    int* rs_v   = rs_e + (NEg + 1);
    int* vid_sorted = rs_v + (NV + 1);                         // NNZ
    int* eid_sorted = vid_sorted + NNZp;                       // NNZ
    unsigned short* Wfrag = (unsigned short*)(eid_sorted + NNZp);  // 56 groups * 512

    // ---- CSR build (cooperative fused hist+scan+partition) + weight frags ----
    hipMemsetAsync(cnt_be, 0, (size_t)(NBE + NBV) * 2 * sizeof(int), stream);
    make_wfrag<<<14, 256, 0, stream>>>(Ws, Wout, W0, Wfrag);
    {
        void* args[] = {(void*)&vertex, (void*)&edges, (void*)&cnt_be, (void*)&cnt_bv,
                        (void*)&gcur_e, (void*)&gcur_v, (void*)&rsb_e, (void*)&rsb_v,
                        (void*)&rs_e, (void*)&rs_v, (void*)&vid_sorted, (void*)&eid_sorted};
        hipLaunchCooperativeKernel((void*)build_coop, dim3(GB), dim3(256), args, 0, stream);
    }
    local_sort_both<<<NBE + NBV, 512, 0, stream>>>(rsb_e, rsb_v, vid_sorted, eid_sorted,
                                                   rs_e, rs_v, degE, scaleE);

    // ---- X = relu(x @ W0 + b0) via MFMA ----
    gemm0_kernel<<<NV / 16, 256, 0, stream>>>(x, Wfrag + 40 * 512, b0, Xbf, X0bf);

    const float betas[4] = {logf(0.5f / 1.f + 1.f), logf(0.5f / 2.f + 1.f),
                            logf(0.5f / 3.f + 1.f), logf(0.5f / 4.f + 1.f)};

    for (int i = 0; i < 3; ++i) {
        gather_ve<<<NEg / 16, 256, 0, stream>>>(rs_e, vid_sorted, Xbf, scaleE, Xebf);
        gather_ev_update<false><<<NV / 16, 256, 0, stream>>>(rs_v, eid_sorted, Xebf, degV,
                                                             X0bf, Wfrag + (size_t)i * 4096,
                                                             Xbf, betas[i],
                                                             nullptr, nullptr, nullptr);
    }
    gather_ve<<<NEg / 16, 256, 0, stream>>>(rs_e, vid_sorted, Xbf, scaleE, Xebf);
    gather_ev_update<true><<<NV / 16, 256, 0, stream>>>(rs_v, eid_sorted, Xebf, degV,
                                                        X0bf, Wfrag + (size_t)3 * 4096,
                                                        Xbf, betas[3],
                                                        Wfrag + 16384, bout, out);
}

// Round 11
// 456.213 us; speedup vs baseline: 1.0651x; 1.0651x over previous
//
#include <hip/hip_runtime.h>
#include <math.h>

constexpr int NV   = 100000;
constexpr int NEg  = 20000;
constexpr int NNZp = 1600000;
constexpr int NF   = 128;
constexpr int NH   = 64;
constexpr int NC   = 40;

constexpr int WE  = 64;                       // e-bucket width (2^6)
constexpr int NBE = (NEg + WE - 1) / WE;      // 313
constexpr int WV  = 256;                      // v-bucket width (2^8)
constexpr int NBV = (NV + WV - 1) / WV;       // 391
constexpr int CAPS = 6400;                    // local_sort stage cap
constexpr int CH   = 2048;                    // partition chunk per block
constexpr int PBLK = (NNZp + CH - 1) / CH;    // 782

typedef __bf16 bf16x8 __attribute__((ext_vector_type(8)));
typedef float  f32x4  __attribute__((ext_vector_type(4)));

// ---- bf16 <-> fp32 helpers (RNE) ----
__device__ __forceinline__ float bf2f(unsigned short u) {
    unsigned int x = ((unsigned int)u) << 16;
    return __builtin_bit_cast(float, x);
}
__device__ __forceinline__ unsigned short f2bf(float f) {
    unsigned int x = __builtin_bit_cast(unsigned int, f);
    x += 0x7fffu + ((x >> 16) & 1u);
    return (unsigned short)(x >> 16);
}
__device__ __forceinline__ ushort4 pack4(float a, float b, float c, float d) {
    ushort4 u; u.x = f2bf(a); u.y = f2bf(b); u.z = f2bf(c); u.w = f2bf(d);
    return u;
}

// ---- inclusive scan of src[0..m) (m<=512) into sc[512] with 256 threads ------
__device__ __forceinline__ void scan512(const int* src, int m, int* sc) {
    const int t = threadIdx.x;
    __syncthreads();                       // protect prior readers of sc
    sc[t]       = (t < m) ? src[t] : 0;
    sc[t + 256] = (t + 256 < m) ? src[t + 256] : 0;
    __syncthreads();
    for (int o = 1; o < 512; o <<= 1) {
        int a = (t >= o) ? sc[t - o] : 0;
        int b = (t + 256 >= o) ? sc[t + 256 - o] : 0;
        __syncthreads();
        sc[t] += a;
        sc[t + 256] += b;
        __syncthreads();
    }
}

// ---------------- coarse histograms ----------------
__global__ __launch_bounds__(256) void coarse_hist(const int* __restrict__ vertex,
                                                   const int* __restrict__ edges,
                                                   int* __restrict__ cnt_be,
                                                   int* __restrict__ cnt_bv) {
    __shared__ int he[NBE], hv[NBV];
    for (int i = threadIdx.x; i < NBE; i += 256) he[i] = 0;
    for (int i = threadIdx.x; i < NBV; i += 256) hv[i] = 0;
    __syncthreads();
    const int base = blockIdx.x * CH;
    const int end  = min(base + CH, NNZp);
    for (int i = base + threadIdx.x; i < end; i += 256) {
        atomicAdd(&he[edges[i]  >> 6], 1);
        atomicAdd(&hv[vertex[i] >> 8], 1);
    }
    __syncthreads();
    for (int i = threadIdx.x; i < NBE; i += 256) if (he[i]) atomicAdd(&cnt_be[i], he[i]);
    for (int i = threadIdx.x; i < NBV; i += 256) if (hv[i]) atomicAdd(&cnt_bv[i], hv[i]);
}

// ---------------- tiny bucket scans ----------------
__global__ __launch_bounds__(512) void scan_buckets(const int* __restrict__ cnt_be,
                                                    const int* __restrict__ cnt_bv,
                                                    int* __restrict__ rsb_e,
                                                    int* __restrict__ rsb_v,
                                                    int* __restrict__ rs_e,
                                                    int* __restrict__ rs_v) {
    __shared__ int s[512];
    const int n      = (blockIdx.x == 0) ? NBE : NBV;
    const int* c     = (blockIdx.x == 0) ? cnt_be : cnt_bv;
    int* r           = (blockIdx.x == 0) ? rsb_e : rsb_v;
    const int t = threadIdx.x;
    int v = (t < n) ? c[t] : 0;
    s[t] = v;
    __syncthreads();
    for (int o = 1; o < 512; o <<= 1) {
        int u = (t >= o) ? s[t - o] : 0;
        __syncthreads();
        s[t] += u;
        __syncthreads();
    }
    if (t < n) r[t] = s[t] - v;
    if (t == 0) {
        r[n] = NNZp;
        if (blockIdx.x == 0) rs_e[NEg] = NNZp;
        else                 rs_v[NV]  = NNZp;
    }
}

// ------- partition, stage-ordered write-back (both sides, one data read) ------
// rank-scatter into bucket-ordered LDS stage, then sequential write-back:
// a wave's 64 lanes write 64 consecutive words -> ~5x fewer store transactions.
__global__ __launch_bounds__(256) void partition_both(const int* __restrict__ vertex,
                                                      const int* __restrict__ edges,
                                                      const int* __restrict__ rsb_e,
                                                      const int* __restrict__ rsb_v,
                                                      int* __restrict__ gcur_e,
                                                      int* __restrict__ gcur_v,
                                                      int* __restrict__ vid_out,
                                                      int* __restrict__ eid_out) {
    __shared__ int h[NBV], gb[NBV], off[NBV], curr[NBV];
    __shared__ int sc[512];
    __shared__ int stage[CH];                  // 8 KB
    const int tid = threadIdx.x;
    const int base = blockIdx.x * CH;
    const int n = min(NNZp - base, CH);
    int re[CH / 256], rv[CH / 256];
#pragma unroll
    for (int j = 0; j < CH / 256; ++j) {
        int i = j * 256 + tid;
        bool ok = i < n;
        re[j] = ok ? edges[base + i] : -1;
        rv[j] = ok ? vertex[base + i] : -1;
    }
    // ================= e side =================
    for (int k = tid; k < NBE; k += 256) h[k] = 0;
    __syncthreads();
#pragma unroll
    for (int j = 0; j < CH / 256; ++j)
        if (re[j] >= 0) atomicAdd(&h[re[j] >> 6], 1);
    scan512(h, NBE, sc);                       // inclusive (syncs internally)
    for (int k = tid; k < NBE; k += 256) {
        int hk = h[k];
        int o = sc[k] - hk;
        off[k] = o; curr[k] = o;
        gb[k] = rsb_e[k] + (hk ? atomicAdd(&gcur_e[k], hk) : 0);
    }
    __syncthreads();
#pragma unroll
    for (int j = 0; j < CH / 256; ++j) {
        if (re[j] >= 0) {
            int k = re[j] >> 6;
            int p = atomicAdd(&curr[k], 1);
            stage[p] = (int)(((unsigned)rv[j] << 15) | (unsigned)re[j]);
        }
    }
    __syncthreads();
    for (int i = tid; i < n; i += 256) {
        unsigned w = (unsigned)stage[i];
        int e = (int)(w & 0x7fffu);
        int k = e >> 6;
        vid_out[gb[k] + (i - off[k])] = (int)(((w >> 15) << 6) | (unsigned)(e & 63));
    }
    __syncthreads();
    // ================= v side =================
    for (int k = tid; k < NBV; k += 256) h[k] = 0;
    __syncthreads();
#pragma unroll
    for (int j = 0; j < CH / 256; ++j)
        if (rv[j] >= 0) atomicAdd(&h[rv[j] >> 8], 1);
    scan512(h, NBV, sc);
    for (int k = tid; k < NBV; k += 256) {
        int hk = h[k];
        int o = sc[k] - hk;
        off[k] = o; curr[k] = o;
        gb[k] = rsb_v[k] + (hk ? atomicAdd(&gcur_v[k], hk) : 0);
    }
    __syncthreads();
#pragma unroll
    for (int j = 0; j < CH / 256; ++j) {
        if (rv[j] >= 0) {
            int k = rv[j] >> 8;
            int p = atomicAdd(&curr[k], 1);
            stage[p] = (int)(((unsigned)re[j] << 17) | (unsigned)rv[j]);
        }
    }
    __syncthreads();
    for (int i = tid; i < n; i += 256) {
        unsigned w = (unsigned)stage[i];
        int v = (int)(w & 0x1ffffu);
        int k = v >> 8;
        eid_out[gb[k] + (i - off[k])] = (int)(((w >> 17) << 8) | (unsigned)(v & 255));
    }
}

// ------- fused per-bucket LDS counting sort -----------------------------------
__global__ __launch_bounds__(512) void local_sort_both(const int* __restrict__ rsb_e,
                                                       const int* __restrict__ rsb_v,
                                                       int* __restrict__ vid_buf,
                                                       int* __restrict__ eid_buf,
                                                       int* __restrict__ rs_e,
                                                       int* __restrict__ rs_v,
                                                       const float* __restrict__ degE,
                                                       float* __restrict__ scaleE) {
    __shared__ int stage[CAPS];
    __shared__ int hist[256], off[256], cnt2[256];
    const bool eside = blockIdx.x < NBE;
    const int b   = eside ? blockIdx.x : blockIdx.x - NBE;
    const int W   = eside ? 64 : 256;
    const int FB  = eside ? 6 : 8;
    const int NID = eside ? NEg : NV;
    const int* rsb = eside ? rsb_e : rsb_v;
    int* buf       = eside ? vid_buf : eid_buf;
    int* rs        = eside ? rs_e : rs_v;
    const int base = rsb[b];
    const int sz   = rsb[b + 1] - base;
    const int tid = threadIdx.x;
    if (tid < 256) { hist[tid] = 0; cnt2[tid] = 0; }
    __syncthreads();
    for (int t = tid; t < sz; t += 512) atomicAdd(&hist[buf[base + t] & (W - 1)], 1);
    __syncthreads();
    {
        int v = (tid < W) ? hist[tid] : 0;
        if (tid < W) off[tid] = v;
        __syncthreads();
        for (int o = 1; o < W; o <<= 1) {
            int u = (tid < W && tid >= o) ? off[tid - o] : 0;
            __syncthreads();
            if (tid < W) off[tid] += u;
            __syncthreads();
        }
        if (tid < W) off[tid] -= v;
    }
    if (tid < W) {
        int gid = b * W + tid;
        if (gid < NID) {
            rs[gid] = base + off[tid];
            if (eside) {
                int c = hist[tid];
                scaleE[gid] = degE[gid] / (float)(c < 1 ? 1 : c);
            }
        }
    }
    __syncthreads();
    for (int t = tid; t < sz; t += 512) {
        int w = buf[base + t];
        int f = w & (W - 1);
        int rk = off[f] + atomicAdd(&cnt2[f], 1);
        stage[rk] = w >> FB;
    }
    __syncthreads();
    for (int t = tid; t < sz; t += 512) buf[base + t] = stage[t];
}

// ------- W fragments (B-operand layout, bf16): Ws MLPs + head + W0 ------------
__global__ __launch_bounds__(256) void make_wfrag(const float* __restrict__ Ws,
                                                  const float* __restrict__ Wout,
                                                  const float* __restrict__ W0,
                                                  unsigned short* __restrict__ frag) {
    int t = blockIdx.x * 256 + threadIdx.x;     // 3584 threads exactly
    int lane = t & 63;
    int g = t >> 6;                             // 0..55
    int quad = lane >> 4, cl = lane & 15;
    unsigned short o[8];
    if (g < 32) {
        int li = g >> 3, w = (g >> 1) & 3, kh = g & 1;
        int n = w * 16 + cl;
#pragma unroll
        for (int j = 0; j < 8; ++j) {
            int k = kh * 32 + quad * 8 + j;
            o[j] = f2bf(Ws[(size_t)li * NH * NH + k * NH + n]);
        }
    } else if (g < 40) {
        int w = (g - 32) >> 1, kh = g & 1;
        int n = w * 16 + cl;
#pragma unroll
        for (int j = 0; j < 8; ++j) {
            int k = kh * 32 + quad * 8 + j;
            o[j] = (n < NC) ? f2bf(Wout[k * NC + n]) : (unsigned short)0;
        }
    } else {
        int w = (g - 40) >> 2, kb = (g - 40) & 3;
        int n = w * 16 + cl;
#pragma unroll
        for (int j = 0; j < 8; ++j) {
            int k = kb * 32 + quad * 8 + j;
            o[j] = f2bf(W0[k * NH + n]);
        }
    }
    unsigned short* dst = frag + (size_t)g * 512 + lane * 8;
    *((ushort4*)dst)       = *(ushort4*)&o[0];
    *((ushort4*)(dst + 4)) = *(ushort4*)&o[4];
}

// ---------------- X = relu(x @ W0 + b0) via MFMA; Xbf = X0bf ------------------
__global__ __launch_bounds__(256) void gemm0_kernel(const float* __restrict__ x,
                                                    const unsigned short* __restrict__ W0frag,
                                                    const float* __restrict__ b0,
                                                    unsigned short* __restrict__ Xbf,
                                                    unsigned short* __restrict__ X0bf) {
    __shared__ unsigned short xs[16][136];    // bf16, stride 136 (16B-aligned rows)
    const int tid = threadIdx.x;
    const int r  = tid >> 4;
    const int c8 = (tid & 15) * 8;
    const int rowbase = blockIdx.x * 16;      // grid = NV/16 exact
    float4 p0 = *((const float4*)(x + (size_t)(rowbase + r) * NF + c8));
    float4 p1 = *((const float4*)(x + (size_t)(rowbase + r) * NF + c8 + 4));
    *((ushort4*)&xs[r][c8])     = pack4(p0.x, p0.y, p0.z, p0.w);
    *((ushort4*)&xs[r][c8 + 4]) = pack4(p1.x, p1.y, p1.z, p1.w);
    __syncthreads();
    const int lane = tid & 63;
    const int wv   = tid >> 6;
    const int quad = lane >> 4;
    const int cl   = lane & 15;
    f32x4 acc = {0.f, 0.f, 0.f, 0.f};
#pragma unroll
    for (int kb = 0; kb < 4; ++kb) {
        bf16x8 a = *((const bf16x8*)&xs[cl][kb * 32 + quad * 8]);
        bf16x8 b = *((const bf16x8*)(W0frag + ((size_t)(wv * 4 + kb) * 64 + lane) * 8));
        acc = __builtin_amdgcn_mfma_f32_16x16x32_bf16(a, b, acc, 0, 0, 0);
    }
    const int col = wv * 16 + cl;
    const float bo = b0[col];
#pragma unroll
    for (int p = 0; p < 4; ++p) {
        const int orow = quad * 4 + p;
        float o = acc[p] + bo;
        o = o > 0.f ? o : 0.f;
        unsigned short ob = f2bf(o);
        const size_t idx = (size_t)(rowbase + orow) * NH + col;
        Xbf[idx]  = ob;
        X0bf[idx] = ob;
    }
}

// ---------------- v->e gather -------------------------------------------------
__global__ __launch_bounds__(256) void gather_ve(const int* __restrict__ rs_e,
                                                 const int* __restrict__ vid_sorted,
                                                 const unsigned short* __restrict__ Xbf,
                                                 const float* __restrict__ scaleE,
                                                 unsigned short* __restrict__ Xebf) {
    const int tid = threadIdx.x;
    const int l16 = tid & 15;
    const int e = blockIdx.x * 16 + (tid >> 4);   // grid = NE/16 exact
    const int b  = rs_e[e];
    const int en = rs_e[e + 1];
    const float s = scaleE[e];
    float ax = 0.f, ay = 0.f, az = 0.f, aw = 0.f;
    int m = b;
    if (m + 4 <= en) {
        int i0 = vid_sorted[m], i1 = vid_sorted[m + 1];
        int i2 = vid_sorted[m + 2], i3 = vid_sorted[m + 3];
        m += 4;
        while (m + 4 <= en) {
            int j0 = vid_sorted[m], j1 = vid_sorted[m + 1];
            int j2 = vid_sorted[m + 2], j3 = vid_sorted[m + 3];
            m += 4;
            ushort4 p = *((const ushort4*)(Xbf + (size_t)i0 * NH) + l16);
            ushort4 q = *((const ushort4*)(Xbf + (size_t)i1 * NH) + l16);
            ushort4 u = *((const ushort4*)(Xbf + (size_t)i2 * NH) + l16);
            ushort4 t = *((const ushort4*)(Xbf + (size_t)i3 * NH) + l16);
            ax += bf2f(p.x) + bf2f(q.x) + bf2f(u.x) + bf2f(t.x);
            ay += bf2f(p.y) + bf2f(q.y) + bf2f(u.y) + bf2f(t.y);
            az += bf2f(p.z) + bf2f(q.z) + bf2f(u.z) + bf2f(t.z);
            aw += bf2f(p.w) + bf2f(q.w) + bf2f(u.w) + bf2f(t.w);
            i0 = j0; i1 = j1; i2 = j2; i3 = j3;
        }
        ushort4 p = *((const ushort4*)(Xbf + (size_t)i0 * NH) + l16);
        ushort4 q = *((const ushort4*)(Xbf + (size_t)i1 * NH) + l16);
        ushort4 u = *((const ushort4*)(Xbf + (size_t)i2 * NH) + l16);
        ushort4 t = *((const ushort4*)(Xbf + (size_t)i3 * NH) + l16);
        ax += bf2f(p.x) + bf2f(q.x) + bf2f(u.x) + bf2f(t.x);
        ay += bf2f(p.y) + bf2f(q.y) + bf2f(u.y) + bf2f(t.y);
        az += bf2f(p.z) + bf2f(q.z) + bf2f(u.z) + bf2f(t.z);
        aw += bf2f(p.w) + bf2f(q.w) + bf2f(u.w) + bf2f(t.w);
    }
    for (; m < en; ++m) {
        ushort4 p = *((const ushort4*)(Xbf + (size_t)vid_sorted[m] * NH) + l16);
        ax += bf2f(p.x); ay += bf2f(p.y); az += bf2f(p.z); aw += bf2f(p.w);
    }
    *((ushort4*)(Xebf + (size_t)e * NH) + l16) = pack4(ax * s, ay * s, az * s, aw * s);
}

// ---------------- e->v gather + normalize/residual + MFMA MLP (+head) ----------
template <bool LAST>
__global__ __launch_bounds__(256) void gather_ev_update(const int* __restrict__ rs_v,
                                                        const int* __restrict__ eid_sorted,
                                                        const unsigned short* __restrict__ Xebf,
                                                        const float* __restrict__ degV,
                                                        const unsigned short* __restrict__ X0bf,
                                                        const unsigned short* __restrict__ WfragL,
                                                        unsigned short* __restrict__ Xbf,
                                                        float beta,
                                                        const unsigned short* __restrict__ WfragH,
                                                        const float* __restrict__ bout,
                                                        float* __restrict__ outp) {
    __shared__ unsigned short xis_bf[16][72];              // bf16, stride 72 (2-way only)
    __shared__ unsigned short xo_bf[LAST ? 16 * 72 : 1];   // final X (LAST only)
    __shared__ float lg[LAST ? 16 * 48 : 1];               // logits (LAST only)
    const int tid = threadIdx.x;
    const int l16 = tid & 15;
    const int r   = tid >> 4;
    const int v = blockIdx.x * 16 + r;        // grid = NV/16 exact
    const int b  = rs_v[v];
    const int en = rs_v[v + 1];
    const float dv = degV[v];
    float ax = 0.f, ay = 0.f, az = 0.f, aw = 0.f;
    int m = b;
    if (m + 4 <= en) {
        int i0 = eid_sorted[m], i1 = eid_sorted[m + 1];
        int i2 = eid_sorted[m + 2], i3 = eid_sorted[m + 3];
        m += 4;
        while (m + 4 <= en) {
            int j0 = eid_sorted[m], j1 = eid_sorted[m + 1];
            int j2 = eid_sorted[m + 2], j3 = eid_sorted[m + 3];
            m += 4;
            ushort4 p = *((const ushort4*)(Xebf + (size_t)i0 * NH) + l16);
            ushort4 q = *((const ushort4*)(Xebf + (size_t)i1 * NH) + l16);
            ushort4 u = *((const ushort4*)(Xebf + (size_t)i2 * NH) + l16);
            ushort4 t = *((const ushort4*)(Xebf + (size_t)i3 * NH) + l16);
            ax += bf2f(p.x) + bf2f(q.x) + bf2f(u.x) + bf2f(t.x);
            ay += bf2f(p.y) + bf2f(q.y) + bf2f(u.y) + bf2f(t.y);
            az += bf2f(p.z) + bf2f(q.z) + bf2f(u.z) + bf2f(t.z);
            aw += bf2f(p.w) + bf2f(q.w) + bf2f(u.w) + bf2f(t.w);
            i0 = j0; i1 = j1; i2 = j2; i3 = j3;
        }
        ushort4 p = *((const ushort4*)(Xebf + (size_t)i0 * NH) + l16);
        ushort4 q = *((const ushort4*)(Xebf + (size_t)i1 * NH) + l16);
        ushort4 u = *((const ushort4*)(Xebf + (size_t)i2 * NH) + l16);
        ushort4 t = *((const ushort4*)(Xebf + (size_t)i3 * NH) + l16);
        ax += bf2f(p.x) + bf2f(q.x) + bf2f(u.x) + bf2f(t.x);
        ay += bf2f(p.y) + bf2f(q.y) + bf2f(u.y) + bf2f(t.y);
        az += bf2f(p.z) + bf2f(q.z) + bf2f(u.z) + bf2f(t.z);
        aw += bf2f(p.w) + bf2f(q.w) + bf2f(u.w) + bf2f(t.w);
    }
    for (; m < en; ++m) {
        ushort4 p = *((const ushort4*)(Xebf + (size_t)eid_sorted[m] * NH) + l16);
        ax += bf2f(p.x); ay += bf2f(p.y); az += bf2f(p.z); aw += bf2f(p.w);
    }
    ax *= dv; ay *= dv; az *= dv; aw *= dv;
    float sq = ax * ax + ay * ay + az * az + aw * aw;
#pragma unroll
    for (int o = 1; o < 16; o <<= 1) sq += __shfl_xor(sq, o);
    float norm = sqrtf(sq);
    float inv = norm > 0.f ? 1.f / norm : 0.f;
    ushort4 u0 = *((const ushort4*)(X0bf + (size_t)v * NH) + l16);
    float xi0 = 0.9f * ax * inv + 0.1f * bf2f(u0.x);
    float xi1 = 0.9f * ay * inv + 0.1f * bf2f(u0.y);
    float xi2 = 0.9f * az * inv + 0.1f * bf2f(u0.z);
    float xi3 = 0.9f * aw * inv + 0.1f * bf2f(u0.w);
    *((ushort4*)&xis_bf[r][l16 * 4]) = pack4(xi0, xi1, xi2, xi3);
    __syncthreads();

    // ---- MFMA MLP: g = xi @ Wl  (M=16, N=64, K=64) ----
    const int lane = tid & 63;
    const int wv   = tid >> 6;
    const int quad = lane >> 4;
    const int cl   = lane & 15;
    bf16x8 bw0 = *((const bf16x8*)(WfragL + ((size_t)(wv * 2 + 0) * 64 + lane) * 8));
    bf16x8 bw1 = *((const bf16x8*)(WfragL + ((size_t)(wv * 2 + 1) * 64 + lane) * 8));
    bf16x8 a0 = *((const bf16x8*)&xis_bf[cl][quad * 8]);
    bf16x8 a1 = *((const bf16x8*)&xis_bf[cl][32 + quad * 8]);
    f32x4 acc = {0.f, 0.f, 0.f, 0.f};
    acc = __builtin_amdgcn_mfma_f32_16x16x32_bf16(a0, bw0, acc, 0, 0, 0);
    acc = __builtin_amdgcn_mfma_f32_16x16x32_bf16(a1, bw1, acc, 0, 0, 0);

    const float ob = 1.f - beta;
    const int col = wv * 16 + cl;
#pragma unroll
    for (int p = 0; p < 4; ++p) {
        const int row = quad * 4 + p;
        float xiv = bf2f(xis_bf[row][col]);
        float o = ob * xiv + beta * acc[p];
        o = o > 0.f ? o : 0.f;
        if (!LAST) {
            Xbf[(size_t)(blockIdx.x * 16 + row) * NH + col] = f2bf(o);
        } else {
            xo_bf[row * 72 + col] = f2bf(o);
        }
    }
    if (LAST) {
        __syncthreads();
        // ---- MFMA output head: logits = Xfinal @ Wout (N padded to 64) ----
        bf16x8 bh0 = *((const bf16x8*)(WfragH + ((size_t)(wv * 2 + 0) * 64 + lane) * 8));
        bf16x8 bh1 = *((const bf16x8*)(WfragH + ((size_t)(wv * 2 + 1) * 64 + lane) * 8));
        bf16x8 ah0 = *((const bf16x8*)&xo_bf[cl * 72 + quad * 8]);
        bf16x8 ah1 = *((const bf16x8*)&xo_bf[cl * 72 + 32 + quad * 8]);
        f32x4 acch = {0.f, 0.f, 0.f, 0.f};
        acch = __builtin_amdgcn_mfma_f32_16x16x32_bf16(ah0, bh0, acch, 0, 0, 0);
        acch = __builtin_amdgcn_mfma_f32_16x16x32_bf16(ah1, bh1, acch, 0, 0, 0);
        if (col < NC) {
            float bo = bout[col];
#pragma unroll
            for (int p = 0; p < 4; ++p) lg[(quad * 4 + p) * 48 + col] = acch[p] + bo;
        }
        __syncthreads();
        // ---- log_softmax: each wave handles 4 rows ----
        const int r0 = wv * 4;
        const bool act = lane < NC;
        float a0s = act ? lg[(r0 + 0) * 48 + lane] : -INFINITY;
        float a1s = act ? lg[(r0 + 1) * 48 + lane] : -INFINITY;
        float a2s = act ? lg[(r0 + 2) * 48 + lane] : -INFINITY;
        float a3s = act ? lg[(r0 + 3) * 48 + lane] : -INFINITY;
        float m0 = a0s, m1 = a1s, m2 = a2s, m3 = a3s;
#pragma unroll
        for (int o = 32; o; o >>= 1) {
            m0 = fmaxf(m0, __shfl_xor(m0, o));
            m1 = fmaxf(m1, __shfl_xor(m1, o));
            m2 = fmaxf(m2, __shfl_xor(m2, o));
            m3 = fmaxf(m3, __shfl_xor(m3, o));
        }
        float e0 = act ? expf(a0s - m0) : 0.f;
        float e1 = act ? expf(a1s - m1) : 0.f;
        float e2 = act ? expf(a2s - m2) : 0.f;
        float e3 = act ? expf(a3s - m3) : 0.f;
#pragma unroll
        for (int o = 32; o; o >>= 1) {
            e0 += __shfl_xor(e0, o);
            e1 += __shfl_xor(e1, o);
            e2 += __shfl_xor(e2, o);
            e3 += __shfl_xor(e3, o);
        }
        if (act) {
            const size_t vb = (size_t)(blockIdx.x * 16 + r0) * NC + lane;
            outp[vb + 0 * NC] = a0s - m0 - logf(e0);
            outp[vb + 1 * NC] = a1s - m1 - logf(e1);
            outp[vb + 2 * NC] = a2s - m2 - logf(e2);
            outp[vb + 3 * NC] = a3s - m3 - logf(e3);
        }
    }
}

extern "C" void kernel_launch(void* const* d_in, const int* in_sizes, int n_in,
                              void* d_out, int out_size, void* d_ws, size_t ws_size,
                              hipStream_t stream) {
    const float* x    = (const float*)d_in[0];
    const float* degE = (const float*)d_in[1];
    const float* degV = (const float*)d_in[2];
    const float* W0   = (const float*)d_in[3];
    const float* b0   = (const float*)d_in[4];
    const float* Ws   = (const float*)d_in[5];
    const float* Wout = (const float*)d_in[6];
    const float* bout = (const float*)d_in[7];
    const int* vertex = (const int*)d_in[8];
    const int* edges  = (const int*)d_in[9];
    float* out = (float*)d_out;

    // workspace layout
    float* scaleE = (float*)d_ws;                              // NEg
    unsigned short* Xbf  = (unsigned short*)(scaleE + NEg);    // NV*NH bf16
    unsigned short* X0bf = Xbf + (size_t)NV * NH;
    unsigned short* Xebf = X0bf + (size_t)NV * NH;             // NE*NH bf16
    int* cnt_be = (int*)(Xebf + (size_t)NEg * NH);
    int* cnt_bv = cnt_be + NBE;
    int* gcur_e = cnt_bv + NBV;
    int* gcur_v = gcur_e + NBE;
    int* rsb_e  = gcur_v + NBV;
    int* rsb_v  = rsb_e + (NBE + 1);
    int* rs_e   = rsb_v + (NBV + 1);
    int* rs_v   = rs_e + (NEg + 1);
    int* vid_sorted = rs_v + (NV + 1);                         // NNZ
    int* eid_sorted = vid_sorted + NNZp;                       // NNZ
    unsigned short* Wfrag = (unsigned short*)(eid_sorted + NNZp);  // 56 groups * 512

    // ---- CSR build + weight fragments ----
    hipMemsetAsync(cnt_be, 0, (size_t)(NBE + NBV) * 2 * sizeof(int), stream);
    make_wfrag<<<14, 256, 0, stream>>>(Ws, Wout, W0, Wfrag);
    coarse_hist<<<PBLK, 256, 0, stream>>>(vertex, edges, cnt_be, cnt_bv);
    scan_buckets<<<2, 512, 0, stream>>>(cnt_be, cnt_bv, rsb_e, rsb_v, rs_e, rs_v);
    partition_both<<<PBLK, 256, 0, stream>>>(vertex, edges, rsb_e, rsb_v,
                                             gcur_e, gcur_v, vid_sorted, eid_sorted);
    local_sort_both<<<NBE + NBV, 512, 0, stream>>>(rsb_e, rsb_v, vid_sorted, eid_sorted,
                                                   rs_e, rs_v, degE, scaleE);

    // ---- X = relu(x @ W0 + b0) via MFMA ----
    gemm0_kernel<<<NV / 16, 256, 0, stream>>>(x, Wfrag + 40 * 512, b0, Xbf, X0bf);

    const float betas[4] = {logf(0.5f / 1.f + 1.f), logf(0.5f / 2.f + 1.f),
                            logf(0.5f / 3.f + 1.f), logf(0.5f / 4.f + 1.f)};

    for (int i = 0; i < 3; ++i) {
        gather_ve<<<NEg / 16, 256, 0, stream>>>(rs_e, vid_sorted, Xbf, scaleE, Xebf);
        gather_ev_update<false><<<NV / 16, 256, 0, stream>>>(rs_v, eid_sorted, Xebf, degV,
                                                             X0bf, Wfrag + (size_t)i * 4096,
                                                             Xbf, betas[i],
                                                             nullptr, nullptr, nullptr);
    }
    gather_ve<<<NEg / 16, 256, 0, stream>>>(rs_e, vid_sorted, Xbf, scaleE, Xebf);
    gather_ev_update<true><<<NV / 16, 256, 0, stream>>>(rs_v, eid_sorted, Xebf, degV,
                                                        X0bf, Wfrag + (size_t)3 * 4096,
                                                        Xbf, betas[3],
                                                        Wfrag + 16384, bout, out);
}

// Round 12
// 453.619 us; speedup vs baseline: 1.0712x; 1.0057x over previous
//
#include <hip/hip_runtime.h>
#include <math.h>

constexpr int NV   = 100000;
constexpr int NEg  = 20000;
constexpr int NNZp = 1600000;
constexpr int NF   = 128;
constexpr int NH   = 64;
constexpr int NC   = 40;

constexpr int WE  = 64;                       // e-bucket width (2^6)
constexpr int NBE = (NEg + WE - 1) / WE;      // 313
constexpr int WV  = 256;                      // v-bucket width (2^8)
constexpr int NBV = (NV + WV - 1) / WV;       // 391
constexpr int CAPS = 6400;                    // local_sort stage cap
constexpr int CH   = 2048;                    // partition chunk per block
constexpr int PBLK = (NNZp + CH - 1) / CH;    // 782

typedef __bf16 bf16x8 __attribute__((ext_vector_type(8)));
typedef float  f32x4  __attribute__((ext_vector_type(4)));

// ---- bf16 <-> fp32 helpers (RNE) ----
__device__ __forceinline__ float bf2f(unsigned short u) {
    unsigned int x = ((unsigned int)u) << 16;
    return __builtin_bit_cast(float, x);
}
__device__ __forceinline__ unsigned short f2bf(float f) {
    unsigned int x = __builtin_bit_cast(unsigned int, f);
    x += 0x7fffu + ((x >> 16) & 1u);
    return (unsigned short)(x >> 16);
}
__device__ __forceinline__ ushort4 pack4(float a, float b, float c, float d) {
    ushort4 u; u.x = f2bf(a); u.y = f2bf(b); u.z = f2bf(c); u.w = f2bf(d);
    return u;
}

// ---------------- coarse histograms ----------------
__global__ __launch_bounds__(256) void coarse_hist(const int* __restrict__ vertex,
                                                   const int* __restrict__ edges,
                                                   int* __restrict__ cnt_be,
                                                   int* __restrict__ cnt_bv) {
    __shared__ int he[NBE], hv[NBV];
    for (int i = threadIdx.x; i < NBE; i += 256) he[i] = 0;
    for (int i = threadIdx.x; i < NBV; i += 256) hv[i] = 0;
    __syncthreads();
    const int base = blockIdx.x * CH;
    const int end  = min(base + CH, NNZp);
    for (int i = base + threadIdx.x; i < end; i += 256) {
        atomicAdd(&he[edges[i]  >> 6], 1);
        atomicAdd(&hv[vertex[i] >> 8], 1);
    }
    __syncthreads();
    for (int i = threadIdx.x; i < NBE; i += 256) if (he[i]) atomicAdd(&cnt_be[i], he[i]);
    for (int i = threadIdx.x; i < NBV; i += 256) if (hv[i]) atomicAdd(&cnt_bv[i], hv[i]);
}

// ---------------- tiny bucket scans ----------------
__global__ __launch_bounds__(512) void scan_buckets(const int* __restrict__ cnt_be,
                                                    const int* __restrict__ cnt_bv,
                                                    int* __restrict__ rsb_e,
                                                    int* __restrict__ rsb_v,
                                                    int* __restrict__ rs_e,
                                                    int* __restrict__ rs_v) {
    __shared__ int s[512];
    const int n      = (blockIdx.x == 0) ? NBE : NBV;
    const int* c     = (blockIdx.x == 0) ? cnt_be : cnt_bv;
    int* r           = (blockIdx.x == 0) ? rsb_e : rsb_v;
    const int t = threadIdx.x;
    int v = (t < n) ? c[t] : 0;
    s[t] = v;
    __syncthreads();
    for (int o = 1; o < 512; o <<= 1) {
        int u = (t >= o) ? s[t - o] : 0;
        __syncthreads();
        s[t] += u;
        __syncthreads();
    }
    if (t < n) r[t] = s[t] - v;
    if (t == 0) {
        r[n] = NNZp;
        if (blockIdx.x == 0) rs_e[NEg] = NNZp;
        else                 rs_v[NV]  = NNZp;
    }
}

// ------- split partition: e-blocks then v-blocks in ONE grid (2*PBLK) ---------
// Half the per-block critical path, double the resident blocks -> latency hiding.
// Staged word packs bucket(9b) | payload(23b), so LDS is only ~9.7 KB.
__global__ __launch_bounds__(256) void partition_split(const int* __restrict__ vertex,
                                                       const int* __restrict__ edges,
                                                       const int* __restrict__ rsb_e,
                                                       const int* __restrict__ rsb_v,
                                                       int* __restrict__ gcur_e,
                                                       int* __restrict__ gcur_v,
                                                       int* __restrict__ vid_out,
                                                       int* __restrict__ eid_out) {
    __shared__ int cur[NBV];                 // 1.53 KB (max of NBE,NBV)
    __shared__ unsigned st[CH];              // 8 KB
    const bool eside = blockIdx.x < PBLK;
    const int  blk   = eside ? blockIdx.x : blockIdx.x - PBLK;
    const int* key   = eside ? edges : vertex;
    const int* val   = eside ? vertex : edges;
    const int* rsb   = eside ? rsb_e : rsb_v;
    int* gcur        = eside ? gcur_e : gcur_v;
    int* outb        = eside ? vid_out : eid_out;
    const int FB     = eside ? 6 : 8;
    const int NB     = eside ? NBE : NBV;
    const int tid = threadIdx.x;
    for (int i = tid; i < NB; i += 256) cur[i] = 0;
    __syncthreads();
    const int base = blk * CH;
    const int n = min(NNZp - base, CH);
    for (int i = tid; i < n; i += 256) {
        int k = key[base + i];
        int v = val[base + i];
        unsigned b = (unsigned)k >> FB;
        atomicAdd(&cur[b], 1);
        st[i] = (b << 23) | ((unsigned)v << FB) | ((unsigned)k & ((1u << FB) - 1u));
    }
    __syncthreads();
    for (int b = tid; b < NB; b += 256) {
        int h = cur[b];
        cur[b] = rsb[b] + (h ? atomicAdd(&gcur[b], h) : 0);
    }
    __syncthreads();
    for (int i = tid; i < n; i += 256) {
        unsigned w = st[i];
        unsigned b = w >> 23;
        int p = atomicAdd(&cur[b], 1);
        outb[p] = (int)(w & 0x7fffffu);
    }
}

// ------- fused per-bucket LDS counting sort -----------------------------------
__global__ __launch_bounds__(512) void local_sort_both(const int* __restrict__ rsb_e,
                                                       const int* __restrict__ rsb_v,
                                                       int* __restrict__ vid_buf,
                                                       int* __restrict__ eid_buf,
                                                       int* __restrict__ rs_e,
                                                       int* __restrict__ rs_v,
                                                       const float* __restrict__ degE,
                                                       float* __restrict__ scaleE) {
    __shared__ int stage[CAPS];
    __shared__ int hist[256], off[256], cnt2[256];
    const bool eside = blockIdx.x < NBE;
    const int b   = eside ? blockIdx.x : blockIdx.x - NBE;
    const int W   = eside ? 64 : 256;
    const int FB  = eside ? 6 : 8;
    const int NID = eside ? NEg : NV;
    const int* rsb = eside ? rsb_e : rsb_v;
    int* buf       = eside ? vid_buf : eid_buf;
    int* rs        = eside ? rs_e : rs_v;
    const int base = rsb[b];
    const int sz   = rsb[b + 1] - base;
    const int tid = threadIdx.x;
    if (tid < 256) { hist[tid] = 0; cnt2[tid] = 0; }
    __syncthreads();
    for (int t = tid; t < sz; t += 512) atomicAdd(&hist[buf[base + t] & (W - 1)], 1);
    __syncthreads();
    {
        int v = (tid < W) ? hist[tid] : 0;
        if (tid < W) off[tid] = v;
        __syncthreads();
        for (int o = 1; o < W; o <<= 1) {
            int u = (tid < W && tid >= o) ? off[tid - o] : 0;
            __syncthreads();
            if (tid < W) off[tid] += u;
            __syncthreads();
        }
        if (tid < W) off[tid] -= v;
    }
    if (tid < W) {
        int gid = b * W + tid;
        if (gid < NID) {
            rs[gid] = base + off[tid];
            if (eside) {
                int c = hist[tid];
                scaleE[gid] = degE[gid] / (float)(c < 1 ? 1 : c);
            }
        }
    }
    __syncthreads();
    for (int t = tid; t < sz; t += 512) {
        int w = buf[base + t];
        int f = w & (W - 1);
        int rk = off[f] + atomicAdd(&cnt2[f], 1);
        stage[rk] = w >> FB;
    }
    __syncthreads();
    for (int t = tid; t < sz; t += 512) buf[base + t] = stage[t];
}

// ------- W fragments (B-operand layout, bf16): Ws MLPs + head + W0 ------------
__global__ __launch_bounds__(256) void make_wfrag(const float* __restrict__ Ws,
                                                  const float* __restrict__ Wout,
                                                  const float* __restrict__ W0,
                                                  unsigned short* __restrict__ frag) {
    int t = blockIdx.x * 256 + threadIdx.x;     // 3584 threads exactly
    int lane = t & 63;
    int g = t >> 6;                             // 0..55
    int quad = lane >> 4, cl = lane & 15;
    unsigned short o[8];
    if (g < 32) {
        int li = g >> 3, w = (g >> 1) & 3, kh = g & 1;
        int n = w * 16 + cl;
#pragma unroll
        for (int j = 0; j < 8; ++j) {
            int k = kh * 32 + quad * 8 + j;
            o[j] = f2bf(Ws[(size_t)li * NH * NH + k * NH + n]);
        }
    } else if (g < 40) {
        int w = (g - 32) >> 1, kh = g & 1;
        int n = w * 16 + cl;
#pragma unroll
        for (int j = 0; j < 8; ++j) {
            int k = kh * 32 + quad * 8 + j;
            o[j] = (n < NC) ? f2bf(Wout[k * NC + n]) : (unsigned short)0;
        }
    } else {
        int w = (g - 40) >> 2, kb = (g - 40) & 3;
        int n = w * 16 + cl;
#pragma unroll
        for (int j = 0; j < 8; ++j) {
            int k = kb * 32 + quad * 8 + j;
            o[j] = f2bf(W0[k * NH + n]);
        }
    }
    unsigned short* dst = frag + (size_t)g * 512 + lane * 8;
    *((ushort4*)dst)       = *(ushort4*)&o[0];
    *((ushort4*)(dst + 4)) = *(ushort4*)&o[4];
}

// ---------------- X = relu(x @ W0 + b0) via MFMA; Xbf = X0bf ------------------
__global__ __launch_bounds__(256) void gemm0_kernel(const float* __restrict__ x,
                                                    const unsigned short* __restrict__ W0frag,
                                                    const float* __restrict__ b0,
                                                    unsigned short* __restrict__ Xbf,
                                                    unsigned short* __restrict__ X0bf) {
    __shared__ unsigned short xs[16][136];    // bf16, stride 136 (16B-aligned rows)
    const int tid = threadIdx.x;
    const int r  = tid >> 4;
    const int c8 = (tid & 15) * 8;
    const int rowbase = blockIdx.x * 16;      // grid = NV/16 exact
    float4 p0 = *((const float4*)(x + (size_t)(rowbase + r) * NF + c8));
    float4 p1 = *((const float4*)(x + (size_t)(rowbase + r) * NF + c8 + 4));
    *((ushort4*)&xs[r][c8])     = pack4(p0.x, p0.y, p0.z, p0.w);
    *((ushort4*)&xs[r][c8 + 4]) = pack4(p1.x, p1.y, p1.z, p1.w);
    __syncthreads();
    const int lane = tid & 63;
    const int wv   = tid >> 6;
    const int quad = lane >> 4;
    const int cl   = lane & 15;
    f32x4 acc = {0.f, 0.f, 0.f, 0.f};
#pragma unroll
    for (int kb = 0; kb < 4; ++kb) {
        bf16x8 a = *((const bf16x8*)&xs[cl][kb * 32 + quad * 8]);
        bf16x8 b = *((const bf16x8*)(W0frag + ((size_t)(wv * 4 + kb) * 64 + lane) * 8));
        acc = __builtin_amdgcn_mfma_f32_16x16x32_bf16(a, b, acc, 0, 0, 0);
    }
    const int col = wv * 16 + cl;
    const float bo = b0[col];
#pragma unroll
    for (int p = 0; p < 4; ++p) {
        const int orow = quad * 4 + p;
        float o = acc[p] + bo;
        o = o > 0.f ? o : 0.f;
        unsigned short ob = f2bf(o);
        const size_t idx = (size_t)(rowbase + orow) * NH + col;
        Xbf[idx]  = ob;
        X0bf[idx] = ob;
    }
}

// ---------------- v->e gather -------------------------------------------------
__global__ __launch_bounds__(256) void gather_ve(const int* __restrict__ rs_e,
                                                 const int* __restrict__ vid_sorted,
                                                 const unsigned short* __restrict__ Xbf,
                                                 const float* __restrict__ scaleE,
                                                 unsigned short* __restrict__ Xebf) {
    const int tid = threadIdx.x;
    const int l16 = tid & 15;
    const int e = blockIdx.x * 16 + (tid >> 4);   // grid = NE/16 exact
    const int b  = rs_e[e];
    const int en = rs_e[e + 1];
    const float s = scaleE[e];
    float ax = 0.f, ay = 0.f, az = 0.f, aw = 0.f;
    int m = b;
    if (m + 4 <= en) {
        int i0 = vid_sorted[m], i1 = vid_sorted[m + 1];
        int i2 = vid_sorted[m + 2], i3 = vid_sorted[m + 3];
        m += 4;
        while (m + 4 <= en) {
            int j0 = vid_sorted[m], j1 = vid_sorted[m + 1];
            int j2 = vid_sorted[m + 2], j3 = vid_sorted[m + 3];
            m += 4;
            ushort4 p = *((const ushort4*)(Xbf + (size_t)i0 * NH) + l16);
            ushort4 q = *((const ushort4*)(Xbf + (size_t)i1 * NH) + l16);
            ushort4 u = *((const ushort4*)(Xbf + (size_t)i2 * NH) + l16);
            ushort4 t = *((const ushort4*)(Xbf + (size_t)i3 * NH) + l16);
            ax += bf2f(p.x) + bf2f(q.x) + bf2f(u.x) + bf2f(t.x);
            ay += bf2f(p.y) + bf2f(q.y) + bf2f(u.y) + bf2f(t.y);
            az += bf2f(p.z) + bf2f(q.z) + bf2f(u.z) + bf2f(t.z);
            aw += bf2f(p.w) + bf2f(q.w) + bf2f(u.w) + bf2f(t.w);
            i0 = j0; i1 = j1; i2 = j2; i3 = j3;
        }
        ushort4 p = *((const ushort4*)(Xbf + (size_t)i0 * NH) + l16);
        ushort4 q = *((const ushort4*)(Xbf + (size_t)i1 * NH) + l16);
        ushort4 u = *((const ushort4*)(Xbf + (size_t)i2 * NH) + l16);
        ushort4 t = *((const ushort4*)(Xbf + (size_t)i3 * NH) + l16);
        ax += bf2f(p.x) + bf2f(q.x) + bf2f(u.x) + bf2f(t.x);
        ay += bf2f(p.y) + bf2f(q.y) + bf2f(u.y) + bf2f(t.y);
        az += bf2f(p.z) + bf2f(q.z) + bf2f(u.z) + bf2f(t.z);
        aw += bf2f(p.w) + bf2f(q.w) + bf2f(u.w) + bf2f(t.w);
    }
    for (; m < en; ++m) {
        ushort4 p = *((const ushort4*)(Xbf + (size_t)vid_sorted[m] * NH) + l16);
        ax += bf2f(p.x); ay += bf2f(p.y); az += bf2f(p.z); aw += bf2f(p.w);
    }
    *((ushort4*)(Xebf + (size_t)e * NH) + l16) = pack4(ax * s, ay * s, az * s, aw * s);
}

// ---------------- e->v gather + normalize/residual + MFMA MLP (+head) ----------
template <bool LAST>
__global__ __launch_bounds__(256) void gather_ev_update(const int* __restrict__ rs_v,
                                                        const int* __restrict__ eid_sorted,
                                                        const unsigned short* __restrict__ Xebf,
                                                        const float* __restrict__ degV,
                                                        const unsigned short* __restrict__ X0bf,
                                                        const unsigned short* __restrict__ WfragL,
                                                        unsigned short* __restrict__ Xbf,
                                                        float beta,
                                                        const unsigned short* __restrict__ WfragH,
                                                        const float* __restrict__ bout,
                                                        float* __restrict__ outp) {
    __shared__ unsigned short xis_bf[16][72];              // bf16, stride 72 (2-way only)
    __shared__ unsigned short xo_bf[LAST ? 16 * 72 : 1];   // final X (LAST only)
    __shared__ float lg[LAST ? 16 * 48 : 1];               // logits (LAST only)
    const int tid = threadIdx.x;
    const int l16 = tid & 15;
    const int r   = tid >> 4;
    const int v = blockIdx.x * 16 + r;        // grid = NV/16 exact
    const int b  = rs_v[v];
    const int en = rs_v[v + 1];
    const float dv = degV[v];
    float ax = 0.f, ay = 0.f, az = 0.f, aw = 0.f;
    int m = b;
    if (m + 4 <= en) {
        int i0 = eid_sorted[m], i1 = eid_sorted[m + 1];
        int i2 = eid_sorted[m + 2], i3 = eid_sorted[m + 3];
        m += 4;
        while (m + 4 <= en) {
            int j0 = eid_sorted[m], j1 = eid_sorted[m + 1];
            int j2 = eid_sorted[m + 2], j3 = eid_sorted[m + 3];
            m += 4;
            ushort4 p = *((const ushort4*)(Xebf + (size_t)i0 * NH) + l16);
            ushort4 q = *((const ushort4*)(Xebf + (size_t)i1 * NH) + l16);
            ushort4 u = *((const ushort4*)(Xebf + (size_t)i2 * NH) + l16);
            ushort4 t = *((const ushort4*)(Xebf + (size_t)i3 * NH) + l16);
            ax += bf2f(p.x) + bf2f(q.x) + bf2f(u.x) + bf2f(t.x);
            ay += bf2f(p.y) + bf2f(q.y) + bf2f(u.y) + bf2f(t.y);
            az += bf2f(p.z) + bf2f(q.z) + bf2f(u.z) + bf2f(t.z);
            aw += bf2f(p.w) + bf2f(q.w) + bf2f(u.w) + bf2f(t.w);
            i0 = j0; i1 = j1; i2 = j2; i3 = j3;
        }
        ushort4 p = *((const ushort4*)(Xebf + (size_t)i0 * NH) + l16);
        ushort4 q = *((const ushort4*)(Xebf + (size_t)i1 * NH) + l16);
        ushort4 u = *((const ushort4*)(Xebf + (size_t)i2 * NH) + l16);
        ushort4 t = *((const ushort4*)(Xebf + (size_t)i3 * NH) + l16);
        ax += bf2f(p.x) + bf2f(q.x) + bf2f(u.x) + bf2f(t.x);
        ay += bf2f(p.y) + bf2f(q.y) + bf2f(u.y) + bf2f(t.y);
        az += bf2f(p.z) + bf2f(q.z) + bf2f(u.z) + bf2f(t.z);
        aw += bf2f(p.w) + bf2f(q.w) + bf2f(u.w) + bf2f(t.w);
    }
    for (; m < en; ++m) {
        ushort4 p = *((const ushort4*)(Xebf + (size_t)eid_sorted[m] * NH) + l16);
        ax += bf2f(p.x); ay += bf2f(p.y); az += bf2f(p.z); aw += bf2f(p.w);
    }
    ax *= dv; ay *= dv; az *= dv; aw *= dv;
    float sq = ax * ax + ay * ay + az * az + aw * aw;
#pragma unroll
    for (int o = 1; o < 16; o <<= 1) sq += __shfl_xor(sq, o);
    float norm = sqrtf(sq);
    float inv = norm > 0.f ? 1.f / norm : 0.f;
    ushort4 u0 = *((const ushort4*)(X0bf + (size_t)v * NH) + l16);
    float xi0 = 0.9f * ax * inv + 0.1f * bf2f(u0.x);
    float xi1 = 0.9f * ay * inv + 0.1f * bf2f(u0.y);
    float xi2 = 0.9f * az * inv + 0.1f * bf2f(u0.z);
    float xi3 = 0.9f * aw * inv + 0.1f * bf2f(u0.w);
    *((ushort4*)&xis_bf[r][l16 * 4]) = pack4(xi0, xi1, xi2, xi3);
    __syncthreads();

    // ---- MFMA MLP: g = xi @ Wl  (M=16, N=64, K=64) ----
    const int lane = tid & 63;
    const int wv   = tid >> 6;
    const int quad = lane >> 4;
    const int cl   = lane & 15;
    bf16x8 bw0 = *((const bf16x8*)(WfragL + ((size_t)(wv * 2 + 0) * 64 + lane) * 8));
    bf16x8 bw1 = *((const bf16x8*)(WfragL + ((size_t)(wv * 2 + 1) * 64 + lane) * 8));
    bf16x8 a0 = *((const bf16x8*)&xis_bf[cl][quad * 8]);
    bf16x8 a1 = *((const bf16x8*)&xis_bf[cl][32 + quad * 8]);
    f32x4 acc = {0.f, 0.f, 0.f, 0.f};
    acc = __builtin_amdgcn_mfma_f32_16x16x32_bf16(a0, bw0, acc, 0, 0, 0);
    acc = __builtin_amdgcn_mfma_f32_16x16x32_bf16(a1, bw1, acc, 0, 0, 0);

    const float ob = 1.f - beta;
    const int col = wv * 16 + cl;
#pragma unroll
    for (int p = 0; p < 4; ++p) {
        const int row = quad * 4 + p;
        float xiv = bf2f(xis_bf[row][col]);
        float o = ob * xiv + beta * acc[p];
        o = o > 0.f ? o : 0.f;
        if (!LAST) {
            Xbf[(size_t)(blockIdx.x * 16 + row) * NH + col] = f2bf(o);
        } else {
            xo_bf[row * 72 + col] = f2bf(o);
        }
    }
    if (LAST) {
        __syncthreads();
        // ---- MFMA output head: logits = Xfinal @ Wout (N padded to 64) ----
        bf16x8 bh0 = *((const bf16x8*)(WfragH + ((size_t)(wv * 2 + 0) * 64 + lane) * 8));
        bf16x8 bh1 = *((const bf16x8*)(WfragH + ((size_t)(wv * 2 + 1) * 64 + lane) * 8));
        bf16x8 ah0 = *((const bf16x8*)&xo_bf[cl * 72 + quad * 8]);
        bf16x8 ah1 = *((const bf16x8*)&xo_bf[cl * 72 + 32 + quad * 8]);
        f32x4 acch = {0.f, 0.f, 0.f, 0.f};
        acch = __builtin_amdgcn_mfma_f32_16x16x32_bf16(ah0, bh0, acch, 0, 0, 0);
        acch = __builtin_amdgcn_mfma_f32_16x16x32_bf16(ah1, bh1, acch, 0, 0, 0);
        if (col < NC) {
            float bo = bout[col];
#pragma unroll
            for (int p = 0; p < 4; ++p) lg[(quad * 4 + p) * 48 + col] = acch[p] + bo;
        }
        __syncthreads();
        // ---- log_softmax: each wave handles 4 rows ----
        const int r0 = wv * 4;
        const bool act = lane < NC;
        float a0s = act ? lg[(r0 + 0) * 48 + lane] : -INFINITY;
        float a1s = act ? lg[(r0 + 1) * 48 + lane] : -INFINITY;
        float a2s = act ? lg[(r0 + 2) * 48 + lane] : -INFINITY;
        float a3s = act ? lg[(r0 + 3) * 48 + lane] : -INFINITY;
        float m0 = a0s, m1 = a1s, m2 = a2s, m3 = a3s;
#pragma unroll
        for (int o = 32; o; o >>= 1) {
            m0 = fmaxf(m0, __shfl_xor(m0, o));
            m1 = fmaxf(m1, __shfl_xor(m1, o));
            m2 = fmaxf(m2, __shfl_xor(m2, o));
            m3 = fmaxf(m3, __shfl_xor(m3, o));
        }
        float e0 = act ? expf(a0s - m0) : 0.f;
        float e1 = act ? expf(a1s - m1) : 0.f;
        float e2 = act ? expf(a2s - m2) : 0.f;
        float e3 = act ? expf(a3s - m3) : 0.f;
#pragma unroll
        for (int o = 32; o; o >>= 1) {
            e0 += __shfl_xor(e0, o);
            e1 += __shfl_xor(e1, o);
            e2 += __shfl_xor(e2, o);
            e3 += __shfl_xor(e3, o);
        }
        if (act) {
            const size_t vb = (size_t)(blockIdx.x * 16 + r0) * NC + lane;
            outp[vb + 0 * NC] = a0s - m0 - logf(e0);
            outp[vb + 1 * NC] = a1s - m1 - logf(e1);
            outp[vb + 2 * NC] = a2s - m2 - logf(e2);
            outp[vb + 3 * NC] = a3s - m3 - logf(e3);
        }
    }
}

extern "C" void kernel_launch(void* const* d_in, const int* in_sizes, int n_in,
                              void* d_out, int out_size, void* d_ws, size_t ws_size,
                              hipStream_t stream) {
    const float* x    = (const float*)d_in[0];
    const float* degE = (const float*)d_in[1];
    const float* degV = (const float*)d_in[2];
    const float* W0   = (const float*)d_in[3];
    const float* b0   = (const float*)d_in[4];
    const float* Ws   = (const float*)d_in[5];
    const float* Wout = (const float*)d_in[6];
    const float* bout = (const float*)d_in[7];
    const int* vertex = (const int*)d_in[8];
    const int* edges  = (const int*)d_in[9];
    float* out = (float*)d_out;

    // workspace layout
    float* scaleE = (float*)d_ws;                              // NEg
    unsigned short* Xbf  = (unsigned short*)(scaleE + NEg);    // NV*NH bf16
    unsigned short* X0bf = Xbf + (size_t)NV * NH;
    unsigned short* Xebf = X0bf + (size_t)NV * NH;             // NE*NH bf16
    int* cnt_be = (int*)(Xebf + (size_t)NEg * NH);
    int* cnt_bv = cnt_be + NBE;
    int* gcur_e = cnt_bv + NBV;
    int* gcur_v = gcur_e + NBE;
    int* rsb_e  = gcur_v + NBV;
    int* rsb_v  = rsb_e + (NBE + 1);
    int* rs_e   = rsb_v + (NBV + 1);
    int* rs_v   = rs_e + (NEg + 1);
    int* vid_sorted = rs_v + (NV + 1);                         // NNZ
    int* eid_sorted = vid_sorted + NNZp;                       // NNZ
    unsigned short* Wfrag = (unsigned short*)(eid_sorted + NNZp);  // 56 groups * 512

    // ---- CSR build + weight fragments ----
    hipMemsetAsync(cnt_be, 0, (size_t)(NBE + NBV) * 2 * sizeof(int), stream);
    make_wfrag<<<14, 256, 0, stream>>>(Ws, Wout, W0, Wfrag);
    coarse_hist<<<PBLK, 256, 0, stream>>>(vertex, edges, cnt_be, cnt_bv);
    scan_buckets<<<2, 512, 0, stream>>>(cnt_be, cnt_bv, rsb_e, rsb_v, rs_e, rs_v);
    partition_split<<<2 * PBLK, 256, 0, stream>>>(vertex, edges, rsb_e, rsb_v,
                                                  gcur_e, gcur_v, vid_sorted, eid_sorted);
    local_sort_both<<<NBE + NBV, 512, 0, stream>>>(rsb_e, rsb_v, vid_sorted, eid_sorted,
                                                   rs_e, rs_v, degE, scaleE);

    // ---- X = relu(x @ W0 + b0) via MFMA ----
    gemm0_kernel<<<NV / 16, 256, 0, stream>>>(x, Wfrag + 40 * 512, b0, Xbf, X0bf);

    const float betas[4] = {logf(0.5f / 1.f + 1.f), logf(0.5f / 2.f + 1.f),
                            logf(0.5f / 3.f + 1.f), logf(0.5f / 4.f + 1.f)};

    for (int i = 0; i < 3; ++i) {
        gather_ve<<<NEg / 16, 256, 0, stream>>>(rs_e, vid_sorted, Xbf, scaleE, Xebf);
        gather_ev_update<false><<<NV / 16, 256, 0, stream>>>(rs_v, eid_sorted, Xebf, degV,
                                                             X0bf, Wfrag + (size_t)i * 4096,
                                                             Xbf, betas[i],
                                                             nullptr, nullptr, nullptr);
    }
    gather_ve<<<NEg / 16, 256, 0, stream>>>(rs_e, vid_sorted, Xbf, scaleE, Xebf);
    gather_ev_update<true><<<NV / 16, 256, 0, stream>>>(rs_v, eid_sorted, Xebf, degV,
                                                        X0bf, Wfrag + (size_t)3 * 4096,
                                                        Xbf, betas[3],
                                                        Wfrag + 16384, bout, out);
}